// Round 10
// baseline (984.897 us; speedup 1.0000x reference)
//
#include <hip/hip_runtime.h>
#include <math.h>

// ---------------------------------------------------------------------------
// VariableRVQ: 4-layer residual VQ, N=131072, D=128, K={1024,1024,512,512}
// d_out layout (floats): [quantized 131072*128][indices 131072*4][loss 4][perp 4][mse 4]
//
// fp16-split MFMA distance GEMM (x.e ~= hx.he + lx.he + hx.le) with exact
// fp32 rescue of near-ties. 512-thread blocks, chunk-level double-buffered
// B staging via global_load_lds, ONE barrier per 64-col chunk.
// Round 8: nf-outer/ks-inner MFMA loop -> only 2 live accumulators
// (acc pressure 32->8 VGPR) so the ~116-reg working set fits under the
// 128-VGPR cap of __launch_bounds__(512,4) without spilling (r7: VGPR=64).
// ---------------------------------------------------------------------------

#define N_ROWS 131072
#define DDIM 128
#define BN 256
#define NTHREADS 512

#define OQ 0
#define OI 16777216
#define OL 17301504
#define OP 17301508
#define OM 17301512

#define RESCUE_EPS 1e-3f

typedef _Float16 f16x8 __attribute__((ext_vector_type(8)));
typedef float f32x4 __attribute__((ext_vector_type(4)));

__device__ __forceinline__ void gl16(const _Float16* g, _Float16* l) {
    __builtin_amdgcn_global_load_lds((const __attribute__((address_space(1))) void*)g,
                                     (__attribute__((address_space(3))) void*)l, 16, 0, 0);
}

// ---------------------------------------------------------------------------
// codebook fp16 split, chunk-major fragment-linear layout:
// chunk c = 64 cols x 128 k, 16384 fp16 (h then l per 2048-block):
//   off = c*16384 + ks*4096 + hl*2048 + nf*512 + lane*8 + i
//   lane = kg*16 + trow;  col = c*64 + nf*16 + trow;  d = ks*32 + kg*8 + i
__global__ void split_cb_kernel(const float* __restrict__ cb,
                                _Float16* __restrict__ out, int K)
{
    const int idx = blockIdx.x * 256 + threadIdx.x;   // over K*128
    const int col = idx >> 7, d = idx & 127;
    const float v = cb[idx];
    const _Float16 h = (_Float16)v;
    const _Float16 l = (_Float16)(v - (float)h);
    const int c = col >> 6, nf = (col >> 4) & 3, trow = col & 15;
    const int ks = d >> 5, kg = (d >> 3) & 3, i = d & 7;
    const size_t off = (size_t)c * 16384 + ks * 4096 + nf * 512 + (kg * 16 + trow) * 8 + i;
    out[off] = h;
    out[off + 2048] = l;
}

// ---------------------------------------------------------------------------
// codebook row norms (exact fp32): one wave per row
__global__ void cbnorm_kernel(const float* __restrict__ cb,
                              float* __restrict__ norms, int K)
{
    const int row  = blockIdx.x * 4 + (threadIdx.x >> 6);
    const int lane = threadIdx.x & 63;
    const float2 v = *(const float2*)(cb + (size_t)row * DDIM + lane * 2);
    float s = fmaf(v.x, v.x, v.y * v.y);
#pragma unroll
    for (int o = 32; o; o >>= 1) s += __shfl_xor(s, o);
    if (lane == 0) norms[row] = s;
}

// ---------------------------------------------------------------------------
// Fused layer: MFMA distance GEMM + argmin(+rescue) + residual update + stats
template<bool LAST>
__global__ __launch_bounds__(512, 4)
void vq_layer_kernel(const float* __restrict__ res_in,   // [N,128]
                     const float* __restrict__ cb,       // [K,128] fp32
                     const _Float16* __restrict__ cbS,   // split fragments
                     const float* __restrict__ cbnorm,   // [K]
                     const int K,
                     const float* __restrict__ x,        // original (LAST)
                     float* res_out,
                     float* __restrict__ idx_out,
                     const int layer,
                     int* __restrict__ hist,
                     float* __restrict__ sumsq)
{
    extern __shared__ char smem[];
    _Float16* Bs   = (_Float16*)smem;          // 2 x 16384 fp16 (64 KB)
    int*      kw   = (int*)(smem + 65536);     // 256
    int*      rlist= (int*)(smem + 66560);     // 256
    int*      nresc= (int*)(smem + 67584);
    float*    wsum = (float*)(smem + 67600);   // 8

    const int tid  = threadIdx.x;
    const int w    = tid >> 6;         // wave 0..7 -> rows w*32..+31
    const int wl   = tid & 63;
    const int trow = tid & 15;
    const int tkg  = (tid >> 4) & 3;
    const int n0   = blockIdx.x * BN;

    if (tid == 0) *nresc = 0;

    // ---- load + split this wave's 32 residual rows into A fragments ----
    f16x8 Ah[2][4], Al[2][4];
#pragma unroll
    for (int mf = 0; mf < 2; ++mf) {
        const int row = n0 + w * 32 + mf * 16 + trow;
        const float* rp = res_in + (size_t)row * DDIM;
#pragma unroll
        for (int ks = 0; ks < 4; ++ks) {
            const int d0 = ks * 32 + tkg * 8;
            const float4 f0 = *(const float4*)(rp + d0);
            const float4 f1 = *(const float4*)(rp + d0 + 4);
            const float vv[8] = {f0.x, f0.y, f0.z, f0.w, f1.x, f1.y, f1.z, f1.w};
#pragma unroll
            for (int i = 0; i < 8; ++i) {
                const _Float16 h = (_Float16)vv[i];
                Ah[mf][ks][i] = h;
                Al[mf][ks][i] = (_Float16)(vv[i] - (float)h);
            }
        }
    }

    // ---- prologue: stage chunk 0 (32 KB, 4 rounds of 8 KB) ----
    {
        const _Float16* src = cbS + w * 512 + wl * 8;
        _Float16* dst = Bs + w * 512;
#pragma unroll
        for (int r = 0; r < 4; ++r)
            gl16(src + r * 4096, dst + r * 4096);
    }
    __syncthreads();

    float m1v[8], m2v[8];
    int   m1k[8];
#pragma unroll
    for (int i = 0; i < 8; ++i) { m1v[i] = 3.4e38f; m2v[i] = 3.4e38f; m1k[i] = 0x7fffffff; }

    const int nchunks = K >> 6;

    for (int c = 0; c < nchunks; ++c) {
        const int cur = c & 1;

        // -- issue next chunk's staging into the other buffer --
        if (c + 1 < nchunks) {
            const _Float16* src = cbS + (size_t)(c + 1) * 16384 + w * 512 + wl * 8;
            _Float16* dst = Bs + (cur ^ 1) * 16384 + w * 512;
#pragma unroll
            for (int r = 0; r < 4; ++r)
                gl16(src + r * 4096, dst + r * 4096);
        }

        const _Float16* Bb = Bs + cur * 16384;

        // nf-outer / ks-inner: only 2 accumulators live at a time
#pragma unroll
        for (int nf = 0; nf < 4; ++nf) {
            f32x4 acc0 = f32x4{0.f, 0.f, 0.f, 0.f};
            f32x4 acc1 = f32x4{0.f, 0.f, 0.f, 0.f};
#pragma unroll
            for (int ks = 0; ks < 4; ++ks) {
                const f16x8 bh = *(const f16x8*)(Bb + ks * 4096 + nf * 512 + wl * 8);
                const f16x8 bl = *(const f16x8*)(Bb + ks * 4096 + 2048 + nf * 512 + wl * 8);
                acc0 = __builtin_amdgcn_mfma_f32_16x16x32_f16(Ah[0][ks], bh, acc0, 0, 0, 0);
                acc1 = __builtin_amdgcn_mfma_f32_16x16x32_f16(Ah[1][ks], bh, acc1, 0, 0, 0);
                acc0 = __builtin_amdgcn_mfma_f32_16x16x32_f16(Al[0][ks], bh, acc0, 0, 0, 0);
                acc1 = __builtin_amdgcn_mfma_f32_16x16x32_f16(Al[1][ks], bh, acc1, 0, 0, 0);
                acc0 = __builtin_amdgcn_mfma_f32_16x16x32_f16(Ah[0][ks], bl, acc0, 0, 0, 0);
                acc1 = __builtin_amdgcn_mfma_f32_16x16x32_f16(Ah[1][ks], bl, acc1, 0, 0, 0);
            }
            // distances + per-lane (min1,k1,min2) tracking for this col group
            const int col = c * 64 + nf * 16 + trow;
            const float nvv = cbnorm[col];
#pragma unroll
            for (int r = 0; r < 4; ++r) {
                const float dv = fmaf(-2.f, acc0[r], nvv);
                if (dv < m1v[r]) { m2v[r] = m1v[r]; m1v[r] = dv; m1k[r] = col; }
                else if (dv < m2v[r]) m2v[r] = dv;
            }
#pragma unroll
            for (int r = 0; r < 4; ++r) {
                const float dv = fmaf(-2.f, acc1[r], nvv);
                const int t8 = 4 + r;
                if (dv < m1v[t8]) { m2v[t8] = m1v[t8]; m1v[t8] = dv; m1k[t8] = col; }
                else if (dv < m2v[t8]) m2v[t8] = dv;
            }
        }

        __syncthreads();   // prefetch landed; old buffer free
    }

    // ---- cross-lane (16-col) merge; flag near-ties for exact rescue ----
#pragma unroll
    for (int t8 = 0; t8 < 8; ++t8) {
        float v1 = m1v[t8], v2 = m2v[t8];
        int   k1 = m1k[t8];
#pragma unroll
        for (int off = 1; off < 16; off <<= 1) {
            const float ov1 = __shfl_xor(v1, off);
            const int   ok1 = __shfl_xor(k1, off);
            const float ov2 = __shfl_xor(v2, off);
            const bool take = (ov1 < v1) || (ov1 == v1 && ok1 < k1);
            const float nm2 = take ? fminf(v1, ov2) : fminf(ov1, v2);
            if (take) { v1 = ov1; k1 = ok1; }
            v2 = nm2;
        }
        if (trow == 0) {
            const int lrow = w * 32 + (t8 >> 2) * 16 + tkg * 4 + (t8 & 3);
            kw[lrow] = k1;
            if (v2 - v1 < RESCUE_EPS) {
                const int p = atomicAdd(nresc, 1);
                rlist[p] = lrow;
            }
        }
    }
    __syncthreads();

    // ---- exact fp32 rescue: one wave scans all K for a flagged row ----
    const int nr = *nresc;
    for (int j = w; j < nr; j += 8) {
        const int lrow = rlist[j];
        const float* rp = res_in + (size_t)(n0 + lrow) * DDIM;
        float best = 3.4e38f; int bestk = 0x7fffffff;
        for (int kk = wl; kk < K; kk += 64) {
            const float* ep = cb + (size_t)kk * DDIM;
            float dot = 0.f;
#pragma unroll 8
            for (int d = 0; d < DDIM; d += 4) {
                const float4 rv = *(const float4*)(rp + d);
                const float4 ev = *(const float4*)(ep + d);
                dot = fmaf(rv.x, ev.x, dot); dot = fmaf(rv.y, ev.y, dot);
                dot = fmaf(rv.z, ev.z, dot); dot = fmaf(rv.w, ev.w, dot);
            }
            const float dv = fmaf(-2.f, dot, cbnorm[kk]);
            if (dv < best) { best = dv; bestk = kk; }   // kk ascending: first-min
        }
#pragma unroll
        for (int off = 1; off < 64; off <<= 1) {
            const float ov = __shfl_xor(best, off);
            const int   ok = __shfl_xor(bestk, off);
            if (ov < best || (ov == best && ok < bestk)) { best = ov; bestk = ok; }
        }
        if (wl == 0) kw[lrow] = bestk;
    }
    __syncthreads();

    // ---- indices + histogram ----
    if (tid < BN) {
        const int bk = kw[tid];
        idx_out[(size_t)(n0 + tid) * 4 + layer] = (float)bk;
        atomicAdd(&hist[bk], 1);
    }

    // ---- residual update (reference fl-arithmetic), sumsq ----
    float ssum = 0.f;
#pragma unroll
    for (int v = 0; v < 16; ++v) {
        const int flat = (v * NTHREADS + tid) * 4;
        const int r  = flat >> 7;
        const int d0 = flat & 127;
        const int k  = kw[r];
        const float4 e  = *(const float4*)(cb + (size_t)k * DDIM + d0);
        const float4 rs = *(const float4*)(res_in + (size_t)(n0 + r) * DDIM + d0);
        // q_st = r + (q - r); res_new = r - q_st   (match reference rounding)
        float4 rn;
        rn.x = rs.x - (rs.x + (e.x - rs.x));
        rn.y = rs.y - (rs.y + (e.y - rs.y));
        rn.z = rs.z - (rs.z + (e.z - rs.z));
        rn.w = rs.w - (rs.w + (e.w - rs.w));
        if (LAST) {
            const float4 xv = *(const float4*)(x + (size_t)(n0 + r) * DDIM + d0);
            float4 q;
            q.x = xv.x - rn.x; q.y = xv.y - rn.y; q.z = xv.z - rn.z; q.w = xv.w - rn.w;
            *(float4*)(res_out + (size_t)(n0 + r) * DDIM + d0) = q;
        } else {
            *(float4*)(res_out + (size_t)(n0 + r) * DDIM + d0) = rn;
        }
        ssum += rn.x * rn.x + rn.y * rn.y + rn.z * rn.z + rn.w * rn.w;
    }
#pragma unroll
    for (int o = 32; o; o >>= 1) ssum += __shfl_xor(ssum, o);
    if (wl == 0) wsum[w] = ssum;
    __syncthreads();
    if (tid == 0) {
        float t = 0.f;
#pragma unroll
        for (int i = 0; i < 8; ++i) t += wsum[i];
        atomicAdd(&sumsq[layer], t);
    }
}

// ---------------------------------------------------------------------------
// scalars: perplexity from histogram, loss/mse from sumsq
__global__ void finalize_kernel(const int* __restrict__ hist,
                                const float* __restrict__ sumsq,
                                float* __restrict__ out)
{
    const int l   = blockIdx.x;
    const int K   = (l < 2) ? 1024 : 512;
    const int off = (l < 2) ? l * 1024 : 2048 + (l - 2) * 512;
    const int tid = threadIdx.x;
    float local = 0.f;
    for (int k = tid; k < K; k += 256) {
        const float p = (float)hist[off + k] * (1.0f / 131072.0f);
        local += p * logf(p + 1e-10f);
    }
#pragma unroll
    for (int o = 32; o; o >>= 1) local += __shfl_xor(local, o);
    __shared__ float w[4];
    if ((tid & 63) == 0) w[tid >> 6] = local;
    __syncthreads();
    if (tid == 0) {
        const float H = w[0] + w[1] + w[2] + w[3];
        out[OP + l] = expf(-H);
        const float mse = sumsq[l] * (1.0f / (131072.0f * 128.0f));
        out[OM + l] = mse;
        out[OL + l] = 1.25f * mse;
    }
}

// ---------------------------------------------------------------------------
extern "C" void kernel_launch(void* const* d_in, const int* in_sizes, int n_in,
                              void* d_out, int out_size, void* d_ws, size_t ws_size,
                              hipStream_t stream)
{
    const float* x = (const float*)d_in[0];
    const float* cbs[4] = {(const float*)d_in[1], (const float*)d_in[2],
                           (const float*)d_in[3], (const float*)d_in[4]};
    const int Ks[4]       = {1024, 1024, 512, 512};
    const int normoff[4]  = {0, 1024, 2048, 2560};
    const size_t cbSoff[4] = {0, 262144, 524288, 655360};  // fp16 units (K*256 each)

    float* out  = (float*)d_out;
    float* qres = out + OQ;        // residual buffer, becomes quantized_out
    float* idxf = out + OI;

    int*      hist  = (int*)d_ws;                    // 3072 ints
    float*    sumsq = (float*)d_ws + 3072;           // 4 floats
    float*    norms = (float*)d_ws + 3076;           // 3072 floats
    _Float16* cbS   = (_Float16*)((float*)d_ws + 6148);  // 786432 fp16 (1.5MB)

    const int LDSB = 67648;
    (void)hipFuncSetAttribute(reinterpret_cast<const void*>(&vq_layer_kernel<false>),
                              hipFuncAttributeMaxDynamicSharedMemorySize, LDSB);
    (void)hipFuncSetAttribute(reinterpret_cast<const void*>(&vq_layer_kernel<true>),
                              hipFuncAttributeMaxDynamicSharedMemorySize, LDSB);

    hipMemsetAsync(d_ws, 0, (3072 + 4) * sizeof(int), stream);

    for (int c = 0; c < 4; ++c) {
        split_cb_kernel<<<(Ks[c] * 128) / 256, 256, 0, stream>>>(cbs[c], cbS + cbSoff[c], Ks[c]);
        cbnorm_kernel<<<Ks[c] / 4, 256, 0, stream>>>(cbs[c], norms + normoff[c], Ks[c]);
    }

    const int grid = N_ROWS / BN;  // 512
    vq_layer_kernel<false><<<grid, NTHREADS, LDSB, stream>>>(
        x,    cbs[0], cbS + cbSoff[0], norms + normoff[0], Ks[0], nullptr,
        qres, idxf, 0, hist + normoff[0], sumsq);
    vq_layer_kernel<false><<<grid, NTHREADS, LDSB, stream>>>(
        qres, cbs[1], cbS + cbSoff[1], norms + normoff[1], Ks[1], nullptr,
        qres, idxf, 1, hist + normoff[1], sumsq);
    vq_layer_kernel<false><<<grid, NTHREADS, LDSB, stream>>>(
        qres, cbs[2], cbS + cbSoff[2], norms + normoff[2], Ks[2], nullptr,
        qres, idxf, 2, hist + normoff[2], sumsq);
    vq_layer_kernel<true><<<grid, NTHREADS, LDSB, stream>>>(
        qres, cbs[3], cbS + cbSoff[3], norms + normoff[3], Ks[3], x,
        qres, idxf, 3, hist + normoff[3], sumsq);

    finalize_kernel<<<4, 256, 0, stream>>>(hist, sumsq, out);
}